// Round 1
// baseline (207.369 us; speedup 1.0000x reference)
//
#include <hip/hip_runtime.h>

// YOLO loss reduction: B=512, 3136 cells/sample, 15 slots/cell, fp32.
// Memory-bound: 192.7 MB read -> ~30 us floor at 6.3 TB/s.
//
// Strategy:
//  - 256-thread blocks stage a 256-cell tile (3840 floats/tensor) into LDS
//    via perfectly coalesced float4 loads (cell stride 60 B defeats direct
//    vector loads; LDS re-layout fixes it).
//  - Each thread consumes one cell from LDS (stride-15 reads = 2 lanes/bank,
//    free on gfx950).
//  - Grid-stride over tiles, per-thread accumulator, wave shuffle reduce,
//    cross-wave LDS reduce, one atomicAdd per block (1024 total).

constexpr int CPT = 256;        // cells per tile
constexpr int TF  = CPT * 15;   // 3840 floats per tile per tensor
#define EPSF 1e-9f

__global__ __launch_bounds__(256) void yolo_loss_kernel(
    const float* __restrict__ o, const float* __restrict__ t,
    float* __restrict__ out_sum, int n_cells)
{
    __shared__ __align__(16) float so[TF];
    __shared__ __align__(16) float st[TF];
    __shared__ float wsum[4];

    const int tid = threadIdx.x;
    const int n_tiles = (n_cells + CPT - 1) / CPT;
    const long lim4 = ((long)n_cells * 15) / 4;   // total float4 count (divisible here)
    const float4* o4 = (const float4*)o;
    const float4* t4 = (const float4*)t;

    float acc = 0.f;

    for (int tile = blockIdx.x; tile < n_tiles; tile += gridDim.x) {
        __syncthreads();   // protect LDS from previous iteration's readers
        const long b4 = (long)tile * (TF / 4);
        #pragma unroll
        for (int i = tid; i < TF / 4; i += 256) {
            long g = b4 + i;
            if (g < lim4) {
                ((float4*)so)[i] = o4[g];
                ((float4*)st)[i] = t4[g];
            }
        }
        __syncthreads();

        const int cell = tile * CPT + tid;
        if (cell < n_cells) {
            const float* oc = so + tid * 15;
            const float* tc = st + tid * 15;
            const float o0 = oc[0];
            if (o0 != 0.f) {
                const float d0 = o0 - tc[0];
                const float dw = sqrtf(oc[2]) - sqrtf(tc[2]);
                const float dh = sqrtf(oc[3]) - sqrtf(tc[3]);
                const float tv = tc[4], ov = oc[4];
                const float conf = -(tv * __logf(ov + EPSF)
                                   + (1.f - tv) * __logf(1.f - ov + EPSF));
                float s = d0 * d0 + dw * dw + dh * dh + conf;
                #pragma unroll
                for (int k = 5; k < 14; ++k) {
                    const float d = tc[k] - oc[k];
                    s += d * d;
                }
                acc += s;
            }
        }
    }

    // wave (64-lane) shuffle reduction
    #pragma unroll
    for (int off = 32; off; off >>= 1) acc += __shfl_down(acc, off, 64);
    if ((tid & 63) == 0) wsum[tid >> 6] = acc;
    __syncthreads();
    if (tid == 0) atomicAdd(out_sum, wsum[0] + wsum[1] + wsum[2] + wsum[3]);
}

extern "C" void kernel_launch(void* const* d_in, const int* in_sizes, int n_in,
                              void* d_out, int out_size, void* d_ws, size_t ws_size,
                              hipStream_t stream) {
    const float* o = (const float*)d_in[0];
    const float* t = (const float*)d_in[1];
    float* out = (float*)d_out;
    const int n = in_sizes[0];
    const int n_cells = n / 15;

    // d_out is poisoned 0xAA before every timed replay -> zero it on-stream.
    hipMemsetAsync(out, 0, sizeof(float), stream);

    const int grid = 1024;  // 4 blocks/CU, ~6 tiles each; 1024 atomics total
    yolo_loss_kernel<<<grid, 256, 0, stream>>>(o, t, out, n_cells);
}